// Round 4
// baseline (445.670 us; speedup 1.0000x reference)
//
#include <hip/hip_runtime.h>

#define BATCH 512
#define TLEN  1024
#define NLAB  64
#define NEGV  -10000.0f

// 4 waves per block, one batch chain per block. The 64x64 log-semiring matvec
// is split by OUTPUT row across waves: wave wid computes y_i, i in
// [16*wid, 16*wid+16). Within a wave, lane = i_local + 16*jg accumulates
// j in [16*jg, 16*jg+16) -> 4 broadcast ds_read_b128 + 16 FMA, then
// shfl_xor(16) + shfl_xor(32) butterfly completes the j-sum in-register.
// Cross-wave exchange: 16-lane ds_write into the OTHER parity buffer + ONE
// raw s_barrier per step (manual lgkmcnt + sched_barrier fences; no
// __syncthreads -> no vmcnt(0) drain, global logit prefetch stays in flight).
// State in scaled-exp space: w = exp(alpha - logS); rescale by s = w[0]
// (broadcast ds_read_b32) every step; logS += logf(s) is off the critical
// path. All f32 -> exact-class numerics (R2 gave absmax 0.0).
__global__ __launch_bounds__(256) void crf_fwd(
    const float* __restrict__ logits,
    const int*   __restrict__ lens,
    const float* __restrict__ trans,
    float*       __restrict__ out)
{
    const int tid  = threadIdx.x;
    const int lane = tid & 63;
    const int wid  = tid >> 6;           // 0..3
    const int il   = lane & 15;          // i_local
    const int jg   = lane >> 4;          // j-group 0..3
    const int i    = wid * 16 + il;      // this lane's output label

    __shared__ __align__(16) float buf[2][NLAB];

    // E fragment: E[i][16*jg + m] = exp(trans[i][16*jg + m]), m = 0..15
    float E[16];
    {
        const float4* t4 = reinterpret_cast<const float4*>(trans + i * NLAB + jg * 16);
        #pragma unroll
        for (int c = 0; c < 4; ++c) {
            float4 v = t4[c];
            E[4*c+0] = __expf(v.x); E[4*c+1] = __expf(v.y);
            E[4*c+2] = __expf(v.z); E[4*c+3] = __expf(v.w);
        }
    }

    const int len = lens[blockIdx.x];
    const float* lg = logits + (size_t)blockIdx.x * TLEN * NLAB + i;
    auto ld = [&](int t) { int tc = t < TLEN ? t : TLEN - 1; return lg[tc * NLAB]; };

    // t = 0 exact: alpha1[i] = logit0[i] + trans[i][start] (start = 62);
    // exp(-10000) flushes to 0, matching the reference's masked init state.
    float a0 = (i == NLAB - 2) ? 0.0f : NEGV;
    if (len > 0) a0 = ld(0) + trans[i * NLAB + (NLAB - 2)];
    if (jg == 0) buf[0][i] = __expf(a0);
    asm volatile("s_waitcnt lgkmcnt(0)");
    __builtin_amdgcn_sched_barrier(0);
    __builtin_amdgcn_s_barrier();
    __builtin_amdgcn_sched_barrier(0);

    float logS = 0.0f;
    int p = 0;

    // 8-deep register prefetch of this lane's logit stream (index i)
    float q[8], e[8];
    #pragma unroll
    for (int k = 0; k < 8; ++k) q[k] = ld(1 + k);
    #pragma unroll
    for (int k = 0; k < 8; ++k) e[k] = __expf(q[k]);

    for (int t0 = 1; t0 < len; t0 += 8) {
        float n[8];
        #pragma unroll
        for (int k = 0; k < 8; ++k) n[k] = ld(t0 + 8 + k);   // stays in flight
        #pragma unroll
        for (int k = 0; k < 8; ++k) {
            if (t0 + k >= len) break;                        // uniform (tail only)
            const float4* W4 = reinterpret_cast<const float4*>(&buf[p][jg * 16]);
            float s  = buf[p][0];                            // broadcast read
            float rs = __builtin_amdgcn_rcpf(s);             // issued early
            float y0 = 0.f, y1 = 0.f, y2 = 0.f, y3 = 0.f;
            #pragma unroll
            for (int c = 0; c < 4; ++c) {
                float4 v = W4[c];                            // broadcast per 16 lanes
                y0 = fmaf(E[4*c+0], v.x, y0);
                y1 = fmaf(E[4*c+1], v.y, y1);
                y2 = fmaf(E[4*c+2], v.z, y2);
                y3 = fmaf(E[4*c+3], v.w, y3);
            }
            float y = (y0 + y1) + (y2 + y3);
            y += __shfl_xor(y, 16);                          // sum jg pairs
            y += __shfl_xor(y, 32);                          // full j-sum
            float wn = y * e[k] * rs;
            logS += __logf(s);                               // off critical path
            if (jg == 0) buf[p ^ 1][i] = wn;
            asm volatile("s_waitcnt lgkmcnt(0)");
            __builtin_amdgcn_sched_barrier(0);
            __builtin_amdgcn_s_barrier();
            __builtin_amdgcn_sched_barrier(0);
            p ^= 1;
        }
        #pragma unroll
        for (int k = 0; k < 8; ++k) q[k] = n[k];
        #pragma unroll
        for (int k = 0; k < 8; ++k) e[k] = __expf(q[k]);
    }

    // epilogue: alpha[j] = logS + log(w[j]) + trans[stop][j]; out = logsumexp
    float wf = buf[p][lane];
    float f  = logS + __logf(wf) + trans[(NLAB - 1) * NLAB + lane];  // w==0 -> -inf ok
    float m = f;
    #pragma unroll
    for (int o = 32; o > 0; o >>= 1) m = fmaxf(m, __shfl_xor(m, o));
    float sum = __expf(f - m);
    #pragma unroll
    for (int o = 32; o > 0; o >>= 1) sum += __shfl_xor(sum, o);
    if (tid == 0) out[blockIdx.x] = m + __logf(sum);
}

extern "C" void kernel_launch(void* const* d_in, const int* in_sizes, int n_in,
                              void* d_out, int out_size, void* d_ws, size_t ws_size,
                              hipStream_t stream) {
    const float* logits = (const float*)d_in[0];
    const int*   lens   = (const int*)d_in[1];
    const float* trans  = (const float*)d_in[2];
    float*       outp   = (float*)d_out;
    crf_fwd<<<BATCH, 256, 0, stream>>>(logits, lens, trans, outp);
}

// Round 5
// 389.198 us; speedup vs baseline: 1.1451x; 1.1451x over previous
//
#include <hip/hip_runtime.h>

#define BATCH 512
#define TLEN  1024
#define NLAB  64
#define NEGV  -10000.0f

// One wave per block, one batch chain per wave. The 64-wide broadcast of the
// state vector w (lane j holds w_j) is done with v_readlane_b32 -> SGPR +
// v_fmac_f32 with SGPR operand: NO LDS, NO barrier, NO memory latency in the
// recurrence. Per step: 64 readlane + 64 FMA + 3 add + 1 mul, pure VALU
// issue-bound (~270 cyc). State in scaled-exp space: w = exp(alpha - logS).
// Rescale every 4 steps by s = w[0]: logS += logf(s), and rcp(s) is FOLDED
// into el (w' = (E.w)*el*rcp(s) == E.(w*rcp(s))*el exactly, linear algebra),
// keeping the readlane chain head clean. f32 range: growth <= e^28 per 4
// steps on top of spread e^12 -> max ~e^40 << f32 max. Numerics identical in
// class to R2 (absmax 0.0): f32 FMA, same 4-accumulator association.
__global__ __launch_bounds__(64) void crf_fwd(
    const float* __restrict__ logits,
    const int*   __restrict__ lens,
    const float* __restrict__ trans,
    float*       __restrict__ out)
{
    const int lane = threadIdx.x;
    const int b = blockIdx.x;

    // E row in registers: Erow[j] = exp(trans[lane][j])
    float Erow[NLAB];
    {
        const float4* tr4 = reinterpret_cast<const float4*>(trans + lane * NLAB);
        #pragma unroll
        for (int q = 0; q < NLAB / 4; ++q) {
            float4 v = tr4[q];
            Erow[4*q+0] = __expf(v.x); Erow[4*q+1] = __expf(v.y);
            Erow[4*q+2] = __expf(v.z); Erow[4*q+3] = __expf(v.w);
        }
    }

    const int len = lens[b];
    const float* lg = logits + (size_t)b * TLEN * NLAB + lane;
    auto ld = [&](int t) { int tc = t < TLEN ? t : TLEN - 1; return lg[tc * NLAB]; };

    // t = 0 exact: alpha1[i] = logit0[i] + trans[i][start] (start = 62);
    // exp(-10000) flushes to 0, matching the reference's masked init state.
    const float tstart = trans[lane * NLAB + (NLAB - 2)];
    float a0 = (lane == NLAB - 2) ? 0.0f : NEGV;
    if (len > 0) a0 = ld(0) + tstart;
    float w = __expf(a0);     // shift M = 0
    float logS = 0.0f;

    // 8-deep register prefetch of this lane's logit stream; exp'd off-path
    float c[8], e[8];
    #pragma unroll
    for (int k = 0; k < 8; ++k) c[k] = ld(1 + k);
    #pragma unroll
    for (int k = 0; k < 8; ++k) e[k] = __expf(c[k]);

    for (int t0 = 1; t0 < len; t0 += 8) {
        float n[8];
        #pragma unroll
        for (int k = 0; k < 8; ++k) n[k] = ld(t0 + 8 + k);   // stays in flight
        #pragma unroll
        for (int k = 0; k < 8; ++k) {
            if (t0 + k >= len) break;                        // uniform (tail only)
            float el = e[k];
            if ((k & 3) == 0) {                              // rescale every 4 steps
                float s = __int_as_float(__builtin_amdgcn_readfirstlane(__float_as_int(w)));
                logS += __logf(s);                           // off critical path
                el *= __builtin_amdgcn_rcpf(s);              // fold rescale into el
            }
            const int wi = __float_as_int(w);
            float y0 = 0.f, y1 = 0.f, y2 = 0.f, y3 = 0.f;
            #pragma unroll
            for (int j = 0; j < NLAB; j += 4) {
                float w0 = __int_as_float(__builtin_amdgcn_readlane(wi, j + 0));
                float w1 = __int_as_float(__builtin_amdgcn_readlane(wi, j + 1));
                float w2 = __int_as_float(__builtin_amdgcn_readlane(wi, j + 2));
                float w3 = __int_as_float(__builtin_amdgcn_readlane(wi, j + 3));
                y0 = fmaf(w0, Erow[j + 0], y0);
                y1 = fmaf(w1, Erow[j + 1], y1);
                y2 = fmaf(w2, Erow[j + 2], y2);
                y3 = fmaf(w3, Erow[j + 3], y3);
            }
            w = ((y0 + y1) + (y2 + y3)) * el;
        }
        #pragma unroll
        for (int k = 0; k < 8; ++k) c[k] = n[k];
        #pragma unroll
        for (int k = 0; k < 8; ++k) e[k] = __expf(c[k]);
    }

    // epilogue: alpha[j] = logS + log(w[j]) + trans[stop][j]; out = logsumexp
    const float tstop = trans[(NLAB - 1) * NLAB + lane];
    float f = logS + __logf(w) + tstop;                      // w==0 -> -inf, ok
    float m = f;
    #pragma unroll
    for (int o = 32; o > 0; o >>= 1) m = fmaxf(m, __shfl_xor(m, o));
    float s = __expf(f - m);
    #pragma unroll
    for (int o = 32; o > 0; o >>= 1) s += __shfl_xor(s, o);
    if (lane == 0) out[b] = m + __logf(s);
}

extern "C" void kernel_launch(void* const* d_in, const int* in_sizes, int n_in,
                              void* d_out, int out_size, void* d_ws, size_t ws_size,
                              hipStream_t stream) {
    const float* logits = (const float*)d_in[0];
    const int*   lens   = (const int*)d_in[1];
    const float* trans  = (const float*)d_in[2];
    float*       outp   = (float*)d_out;
    crf_fwd<<<BATCH, NLAB, 0, stream>>>(logits, lens, trans, outp);
}

// Round 6
// 344.526 us; speedup vs baseline: 1.2936x; 1.1297x over previous
//
#include <hip/hip_runtime.h>

#define BATCH 512
#define TLEN  1024
#define NLAB  64
#define NEGV  -10000.0f

// Rotate-within-16-row DPP, fused into the consumer. Same textual modifier is
// used for the setup index probe (mov) and the loop fmac, so whatever
// direction/semantics row_ror has, E's layout matches it exactly.
#define ROR_MOV(dst, src, K) \
  asm("v_mov_b32_dpp %0, %1 row_ror:" #K " row_mask:0xf bank_mask:0xf" : "=v"(dst) : "v"(src))
#define ROR_FMAC(acc, w, e, K) \
  asm("v_fmac_f32_dpp %0, %1, %2 row_ror:" #K " row_mask:0xf bank_mask:0xf" : "+v"(acc) : "v"(w), "v"(e))

__device__ __forceinline__ void swap32f(float &dst, float &src) {
  asm("v_permlane32_swap_b32 %0, %1" : "+v"(dst), "+v"(src));
}
__device__ __forceinline__ void swap16f(float &dst, float &src) {
  asm("v_permlane16_swap_b32 %0, %1" : "+v"(dst), "+v"(src));
}
__device__ __forceinline__ void swap32u(unsigned &dst, unsigned &src) {
  asm("v_permlane32_swap_b32 %0, %1" : "+v"(dst), "+v"(src));
}
__device__ __forceinline__ void swap16u(unsigned &dst, unsigned &src) {
  asm("v_permlane16_swap_b32 %0, %1" : "+v"(dst), "+v"(src));
}

// Eq[k] = exp(trans[lane][idx]) where idx is whatever source index the
// identical row_ror:k DPP presents at this lane for pattern register S.
#define SETUP_PHASE(Eq, S)                                  \
  do {                                                      \
    unsigned r_;                                            \
    Eq[0] = __expf(tr[(S)]);                                \
    ROR_MOV(r_, (S), 1);  Eq[1]  = __expf(tr[r_]);          \
    ROR_MOV(r_, (S), 2);  Eq[2]  = __expf(tr[r_]);          \
    ROR_MOV(r_, (S), 3);  Eq[3]  = __expf(tr[r_]);          \
    ROR_MOV(r_, (S), 4);  Eq[4]  = __expf(tr[r_]);          \
    ROR_MOV(r_, (S), 5);  Eq[5]  = __expf(tr[r_]);          \
    ROR_MOV(r_, (S), 6);  Eq[6]  = __expf(tr[r_]);          \
    ROR_MOV(r_, (S), 7);  Eq[7]  = __expf(tr[r_]);          \
    ROR_MOV(r_, (S), 8);  Eq[8]  = __expf(tr[r_]);          \
    ROR_MOV(r_, (S), 9);  Eq[9]  = __expf(tr[r_]);          \
    ROR_MOV(r_, (S), 10); Eq[10] = __expf(tr[r_]);          \
    ROR_MOV(r_, (S), 11); Eq[11] = __expf(tr[r_]);          \
    ROR_MOV(r_, (S), 12); Eq[12] = __expf(tr[r_]);          \
    ROR_MOV(r_, (S), 13); Eq[13] = __expf(tr[r_]);          \
    ROR_MOV(r_, (S), 14); Eq[14] = __expf(tr[r_]);          \
    ROR_MOV(r_, (S), 15); Eq[15] = __expf(tr[r_]);          \
  } while (0)

// 16 fused fmac-with-rotate; accumulator = k&3 keeps dep distance 4 (8 cyc).
#define PHASE(T, Eq)                 \
  y0 = fmaf((T), Eq[0], y0);         \
  ROR_FMAC(y1, (T), Eq[1], 1);       \
  ROR_FMAC(y2, (T), Eq[2], 2);       \
  ROR_FMAC(y3, (T), Eq[3], 3);       \
  ROR_FMAC(y0, (T), Eq[4], 4);       \
  ROR_FMAC(y1, (T), Eq[5], 5);       \
  ROR_FMAC(y2, (T), Eq[6], 6);       \
  ROR_FMAC(y3, (T), Eq[7], 7);       \
  ROR_FMAC(y0, (T), Eq[8], 8);       \
  ROR_FMAC(y1, (T), Eq[9], 9);       \
  ROR_FMAC(y2, (T), Eq[10], 10);     \
  ROR_FMAC(y3, (T), Eq[11], 11);     \
  ROR_FMAC(y0, (T), Eq[12], 12);     \
  ROR_FMAC(y1, (T), Eq[13], 13);     \
  ROR_FMAC(y2, (T), Eq[14], 14);     \
  ROR_FMAC(y3, (T), Eq[15], 15);

// One wave per block, one chain per wave, zero LDS in the recurrence.
// Per step: 2 mov + 3 permlane_swap build T0..T3 (each = one 16-group of w
// replicated to all rows), then 64 v_fmac_f32_dpp row_ror:k do the 64x64
// matvec entirely on the VALU. State in scaled-exp space (f32, exact class:
// R2/R5 scored absmax 0.0); rescale every 4 steps folded into el; logits
// prefetched 8 deep with exp off the critical path.
__global__ __launch_bounds__(64) void crf_fwd(
    const float* __restrict__ logits,
    const int*   __restrict__ lens,
    const float* __restrict__ trans,
    float*       __restrict__ out)
{
    const int lane = threadIdx.x;
    const int b = blockIdx.x;
    const float* tr = trans + lane * NLAB;

    // pattern probe: run the exact swap sequence on 'lane' to learn which
    // register carries which source group under the HW's swap semantics
    unsigned pa = (unsigned)lane, pb, pc, pd;
    pb = pa; swap32u(pb, pa);
    pc = pa; swap16u(pc, pa);
    pd = pb; swap16u(pd, pb);

    float E0[16], E1[16], E2[16], E3[16];
    SETUP_PHASE(E0, pc);
    SETUP_PHASE(E1, pa);
    SETUP_PHASE(E2, pd);
    SETUP_PHASE(E3, pb);

    const int len = lens[b];
    const float* lg = logits + (size_t)b * TLEN * NLAB + lane;
    auto ld = [&](int t) { int tc = t < TLEN ? t : TLEN - 1; return lg[tc * NLAB]; };

    auto matvec = [&](float wv) -> float {
        float ta = wv, tb, tc, td;
        tb = ta; swap32f(tb, ta);
        tc = ta; swap16f(tc, ta);
        td = tb; swap16f(td, tb);
        float y0 = 0.f, y1 = 0.f, y2 = 0.f, y3 = 0.f;
        PHASE(tc, E0)
        PHASE(ta, E1)
        PHASE(td, E2)
        PHASE(tb, E3)
        return (y0 + y1) + (y2 + y3);
    };

    // t = 0 exact: alpha1[i] = logit0[i] + trans[i][start] (start = 62);
    // exp(-10000) flushes to 0, matching the reference's masked init state.
    const float tstart = tr[NLAB - 2];
    float a0 = (lane == NLAB - 2) ? 0.0f : NEGV;
    if (len > 0) a0 = ld(0) + tstart;
    float w = __expf(a0);     // shift M = 0
    float logS = 0.0f;

    float c[8], e[8];
    #pragma unroll
    for (int k = 0; k < 8; ++k) c[k] = ld(1 + k);
    #pragma unroll
    for (int k = 0; k < 8; ++k) e[k] = __expf(c[k]);

    for (int t0 = 1; t0 < len; t0 += 8) {
        float n[8];
        #pragma unroll
        for (int k = 0; k < 8; ++k) n[k] = ld(t0 + 8 + k);   // stays in flight
        #pragma unroll
        for (int k = 0; k < 8; ++k) {
            if (t0 + k >= len) break;                        // uniform (tail only)
            float el = e[k];
            if ((k & 3) == 0) {                              // rescale every 4 steps
                float s = __int_as_float(__builtin_amdgcn_readfirstlane(__float_as_int(w)));
                logS += __logf(s);                           // off critical path
                el *= __builtin_amdgcn_rcpf(s);              // fold rescale into el
            }
            w = matvec(w) * el;
        }
        #pragma unroll
        for (int k = 0; k < 8; ++k) c[k] = n[k];
        #pragma unroll
        for (int k = 0; k < 8; ++k) e[k] = __expf(c[k]);
    }

    // epilogue: alpha[j] = logS + log(w[j]) + trans[stop][j]; out = logsumexp
    const float tstop = trans[(NLAB - 1) * NLAB + lane];
    float f = logS + __logf(w) + tstop;                      // w==0 -> -inf, ok
    float m = f;
    #pragma unroll
    for (int o = 32; o > 0; o >>= 1) m = fmaxf(m, __shfl_xor(m, o));
    float s = __expf(f - m);
    #pragma unroll
    for (int o = 32; o > 0; o >>= 1) s += __shfl_xor(s, o);
    if (lane == 0) out[b] = m + __logf(s);
}

extern "C" void kernel_launch(void* const* d_in, const int* in_sizes, int n_in,
                              void* d_out, int out_size, void* d_ws, size_t ws_size,
                              hipStream_t stream) {
    const float* logits = (const float*)d_in[0];
    const int*   lens   = (const int*)d_in[1];
    const float* trans  = (const float*)d_in[2];
    float*       outp   = (float*)d_out;
    crf_fwd<<<BATCH, NLAB, 0, stream>>>(logits, lens, trans, outp);
}

// Round 7
// 341.432 us; speedup vs baseline: 1.3053x; 1.0091x over previous
//
#include <hip/hip_runtime.h>

#define BATCH 512
#define TLEN  1024
#define NLAB  64
#define NEGV  -10000.0f

// Rotate-within-16-row DPP fused into the consumer FMA. Same textual modifier
// is used for the setup index probe (mov) and the loop fmac, so whatever
// semantics row_ror has, E's layout matches it exactly.
#define ROR_MOV(dst, src, K) \
  asm("v_mov_b32_dpp %0, %1 row_ror:" #K " row_mask:0xf bank_mask:0xf" : "=v"(dst) : "v"(src))
#define ROR_FMAC(acc, w, e, K) \
  asm("v_fmac_f32_dpp %0, %1, %2 row_ror:" #K " row_mask:0xf bank_mask:0xf" : "+v"(acc) : "v"(w), "v"(e))

__device__ __forceinline__ void swap32f(float &dst, float &src) {
  asm("v_permlane32_swap_b32 %0, %1" : "+v"(dst), "+v"(src));
}
__device__ __forceinline__ void swap16f(float &dst, float &src) {
  asm("v_permlane16_swap_b32 %0, %1" : "+v"(dst), "+v"(src));
}
__device__ __forceinline__ void swap32u(unsigned &dst, unsigned &src) {
  asm("v_permlane32_swap_b32 %0, %1" : "+v"(dst), "+v"(src));
}
__device__ __forceinline__ void swap16u(unsigned &dst, unsigned &src) {
  asm("v_permlane16_swap_b32 %0, %1" : "+v"(dst), "+v"(src));
}

#define SETUP_PHASE(Eq, S)                                  \
  do {                                                      \
    unsigned r_;                                            \
    Eq[0] = __expf(tr[(S)]);                                \
    ROR_MOV(r_, (S), 1);  Eq[1]  = __expf(tr[r_]);          \
    ROR_MOV(r_, (S), 2);  Eq[2]  = __expf(tr[r_]);          \
    ROR_MOV(r_, (S), 3);  Eq[3]  = __expf(tr[r_]);          \
    ROR_MOV(r_, (S), 4);  Eq[4]  = __expf(tr[r_]);          \
    ROR_MOV(r_, (S), 5);  Eq[5]  = __expf(tr[r_]);          \
    ROR_MOV(r_, (S), 6);  Eq[6]  = __expf(tr[r_]);          \
    ROR_MOV(r_, (S), 7);  Eq[7]  = __expf(tr[r_]);          \
    ROR_MOV(r_, (S), 8);  Eq[8]  = __expf(tr[r_]);          \
    ROR_MOV(r_, (S), 9);  Eq[9]  = __expf(tr[r_]);          \
    ROR_MOV(r_, (S), 10); Eq[10] = __expf(tr[r_]);          \
    ROR_MOV(r_, (S), 11); Eq[11] = __expf(tr[r_]);          \
    ROR_MOV(r_, (S), 12); Eq[12] = __expf(tr[r_]);          \
    ROR_MOV(r_, (S), 13); Eq[13] = __expf(tr[r_]);          \
    ROR_MOV(r_, (S), 14); Eq[14] = __expf(tr[r_]);          \
    ROR_MOV(r_, (S), 15); Eq[15] = __expf(tr[r_]);          \
  } while (0)

// 16 fused fmac-with-rotate; 8-accumulator round-robin -> dependent reuse
// distance 8 instrs (16 cyc) >> fmac-DPP result latency: no RAW stalls.
#define PHASE(T, Eq)                 \
  y0 = fmaf((T), Eq[0], y0);         \
  ROR_FMAC(y1, (T), Eq[1], 1);       \
  ROR_FMAC(y2, (T), Eq[2], 2);       \
  ROR_FMAC(y3, (T), Eq[3], 3);       \
  ROR_FMAC(y4, (T), Eq[4], 4);       \
  ROR_FMAC(y5, (T), Eq[5], 5);       \
  ROR_FMAC(y6, (T), Eq[6], 6);       \
  ROR_FMAC(y7, (T), Eq[7], 7);       \
  ROR_FMAC(y0, (T), Eq[8], 8);       \
  ROR_FMAC(y1, (T), Eq[9], 9);       \
  ROR_FMAC(y2, (T), Eq[10], 10);     \
  ROR_FMAC(y3, (T), Eq[11], 11);     \
  ROR_FMAC(y4, (T), Eq[12], 12);     \
  ROR_FMAC(y5, (T), Eq[13], 13);     \
  ROR_FMAC(y6, (T), Eq[14], 14);     \
  ROR_FMAC(y7, (T), Eq[15], 15);

// One wave per block, one chain per wave, zero LDS in the recurrence.
// Per step: 5 permlane/mov build T0..T3 (each = one 16-group of w replicated
// to all rows) + 64 v_fmac_f32_dpp row_ror (8-acc round robin) + tree reduce
// + 1 mul. State in scaled-exp space (f32); rescale every 4 steps folded into
// el (off critical path); logits prefetched 8 deep, exp'd off-path. Main loop
// runs full 8-step chunks unconditionally (no per-step branch); tail separate.
__global__ __launch_bounds__(64) void crf_fwd(
    const float* __restrict__ logits,
    const int*   __restrict__ lens,
    const float* __restrict__ trans,
    float*       __restrict__ out)
{
    const int lane = threadIdx.x;
    const int b = blockIdx.x;
    const float* tr = trans + lane * NLAB;

    // pattern probe: run the exact swap sequence on 'lane' to learn which
    // register carries which source group under the HW's swap semantics
    unsigned pa = (unsigned)lane, pb, pc, pd;
    pb = pa; swap32u(pb, pa);
    pc = pa; swap16u(pc, pa);
    pd = pb; swap16u(pd, pb);

    float E0[16], E1[16], E2[16], E3[16];
    SETUP_PHASE(E0, pc);
    SETUP_PHASE(E1, pa);
    SETUP_PHASE(E2, pd);
    SETUP_PHASE(E3, pb);

    const int len = lens[b];
    const float* lg = logits + (size_t)b * TLEN * NLAB + lane;
    auto ld = [&](int t) { int tc = t < TLEN ? t : TLEN - 1; return lg[tc * NLAB]; };

    auto matvec = [&](float wv) -> float {
        float ta = wv, tb, tc, td;
        tb = ta; swap32f(tb, ta);
        tc = ta; swap16f(tc, ta);
        td = tb; swap16f(td, tb);
        float y0 = 0.f, y1 = 0.f, y2 = 0.f, y3 = 0.f;
        float y4 = 0.f, y5 = 0.f, y6 = 0.f, y7 = 0.f;
        PHASE(tc, E0)
        PHASE(ta, E1)
        PHASE(td, E2)
        PHASE(tb, E3)
        return ((y0 + y1) + (y2 + y3)) + ((y4 + y5) + (y6 + y7));
    };

    // t = 0 exact: alpha1[i] = logit0[i] + trans[i][start] (start = 62);
    // exp(-10000) flushes to 0, matching the reference's masked init state.
    const float tstart = tr[NLAB - 2];
    float a0 = (lane == NLAB - 2) ? 0.0f : NEGV;
    if (len > 0) a0 = ld(0) + tstart;
    float w = __expf(a0);     // shift M = 0
    float logS = 0.0f;

    float c[8], e[8];
    #pragma unroll
    for (int k = 0; k < 8; ++k) c[k] = ld(1 + k);
    #pragma unroll
    for (int k = 0; k < 8; ++k) e[k] = __expf(c[k]);

    int t0 = 1;
    for (; t0 + 8 <= len; t0 += 8) {          // full chunks: no per-step branch
        float n[8];
        #pragma unroll
        for (int k = 0; k < 8; ++k) n[k] = ld(t0 + 8 + k);   // stays in flight
        #pragma unroll
        for (int k = 0; k < 8; ++k) {
            float el = e[k];
            if ((k & 3) == 0) {                              // rescale every 4 steps
                float s = __int_as_float(__builtin_amdgcn_readfirstlane(__float_as_int(w)));
                logS += __logf(s);                           // off critical path
                el *= __builtin_amdgcn_rcpf(s);              // fold rescale into el
            }
            w = matvec(w) * el;
        }
        #pragma unroll
        for (int k = 0; k < 8; ++k) c[k] = n[k];
        #pragma unroll
        for (int k = 0; k < 8; ++k) e[k] = __expf(c[k]);
    }
    #pragma unroll
    for (int k = 0; k < 8; ++k) {                            // tail (< 8 steps)
        if (t0 + k >= len) break;
        float el = e[k];
        if ((k & 3) == 0) {
            float s = __int_as_float(__builtin_amdgcn_readfirstlane(__float_as_int(w)));
            logS += __logf(s);
            el *= __builtin_amdgcn_rcpf(s);
        }
        w = matvec(w) * el;
    }

    // epilogue: alpha[j] = logS + log(w[j]) + trans[stop][j]; out = logsumexp
    const float tstop = trans[(NLAB - 1) * NLAB + lane];
    float f = logS + __logf(w) + tstop;                      // w==0 -> -inf, ok
    float m = f;
    #pragma unroll
    for (int o = 32; o > 0; o >>= 1) m = fmaxf(m, __shfl_xor(m, o));
    float s = __expf(f - m);
    #pragma unroll
    for (int o = 32; o > 0; o >>= 1) s += __shfl_xor(s, o);
    if (lane == 0) out[b] = m + __logf(s);
}

extern "C" void kernel_launch(void* const* d_in, const int* in_sizes, int n_in,
                              void* d_out, int out_size, void* d_ws, size_t ws_size,
                              hipStream_t stream) {
    const float* logits = (const float*)d_in[0];
    const int*   lens   = (const int*)d_in[1];
    const float* trans  = (const float*)d_in[2];
    float*       outp   = (float*)d_out;
    crf_fwd<<<BATCH, NLAB, 0, stream>>>(logits, lens, trans, outp);
}